// Round 4
// baseline (3768.889 us; speedup 1.0000x reference)
//
#include <hip/hip_runtime.h>
#include <hip/hip_bf16.h>

#define N_NODES 50000
#define N_EDGES 600000
#define HID 128
#define HEADS 8
#define OUTC 16
#define NEG_SLOPE 0.2f
#define BN_EPS 1e-5f

typedef __attribute__((ext_vector_type(8))) short short8;
typedef __attribute__((ext_vector_type(4))) float floatx4;

__device__ __forceinline__ float bf_lo(unsigned int v) { return __uint_as_float(v << 16); }
__device__ __forceinline__ float bf_hi(unsigned int v) { return __uint_as_float(v & 0xffff0000u); }

__device__ __forceinline__ short f2bfs(float v) {
    __hip_bfloat16 b = __float2bfloat16(v);
    return *reinterpret_cast<short*>(&b);
}

// ---------------- fused: edge histogram + weight prep ----------------
__global__ void k_hist_prep(const int* __restrict__ dst, int* __restrict__ deg, int e, int nb_e,
                            const float* __restrict__ W, const float* __restrict__ asrc,
                            const float* __restrict__ adst,
                            __hip_bfloat16* __restrict__ Wt, __hip_bfloat16* __restrict__ WAT) {
    if ((int)blockIdx.x < nb_e) {
        int i = blockIdx.x * 256 + threadIdx.x;
        if (i < e) atomicAdd(&deg[dst[i]], 1);
        return;
    }
    int i = (blockIdx.x - nb_e) * 256 + threadIdx.x;
    if (i < 3 * 16384) {
        int l = i >> 14, r = i & 16383, n = r >> 7, k = r & 127;
        Wt[i] = __float2bfloat16(W[l * 16384 + k * 128 + n]);
    } else {
        int j2 = i - 3 * 16384;
        if (j2 < 3 * 2048) {
            int l = j2 >> 11, r = j2 & 2047, j = r >> 7, k = r & 127;
            const float* att = (j < 8) ? (asrc + l * 128 + j * 16) : (adst + l * 128 + (j - 8) * 16);
            const float* Wrow = W + l * 16384 + k * 128 + (j & 7) * 16;
            float sum = 0.f;
#pragma unroll
            for (int c = 0; c < 16; c++) sum += Wrow[c] * att[c];
            WAT[j2] = __float2bfloat16(sum);
        }
    }
}

// ---------------- CSR scans ----------------
__global__ void k_scan1(const int* __restrict__ deg, int* __restrict__ incl,
                        int* __restrict__ partials, int n) {
    __shared__ int sh[512];
    int i = blockIdx.x * 512 + threadIdx.x;
    int v = (i < n) ? deg[i] : 0;
    sh[threadIdx.x] = v;
    __syncthreads();
    for (int off = 1; off < 512; off <<= 1) {
        int t = (threadIdx.x >= off) ? sh[threadIdx.x - off] : 0;
        __syncthreads();
        sh[threadIdx.x] += t;
        __syncthreads();
    }
    if (i < n) incl[i] = sh[threadIdx.x];
    if (threadIdx.x == 511) partials[blockIdx.x] = sh[511];
}

// fused scan2+scan3: every block redundantly exclusive-scans the (<=128)
// block partials in LDS, then applies its own offset.
__global__ void k_scan23(const int* __restrict__ deg, const int* __restrict__ incl,
                         const int* __restrict__ partials, int* __restrict__ row_ptr,
                         int* __restrict__ cursor, int n, int e_total, int nb) {
    __shared__ int sp[128];
    int t = threadIdx.x;   // 512
    int orig = 0;
    if (t < 128) {
        orig = (t < nb) ? partials[t] : 0;
        sp[t] = orig;
    }
    __syncthreads();
    for (int off = 1; off < 128; off <<= 1) {
        int v = (t < 128 && t >= off) ? sp[t - off] : 0;
        __syncthreads();
        if (t < 128) sp[t] += v;
        __syncthreads();
    }
    if (t < 128) sp[t] -= orig;   // exclusive
    __syncthreads();
    int i = blockIdx.x * 512 + t;
    if (i < n) {
        int rp = incl[i] - deg[i] + sp[blockIdx.x];
        row_ptr[i] = rp;
        cursor[i] = rp;
    }
    if (i == 0) row_ptr[n] = e_total;
}

__global__ void k_scatter(const int* __restrict__ src, const int* __restrict__ dst,
                          int* __restrict__ cursor, int* __restrict__ col_src, int e) {
    int i = blockIdx.x * 256 + threadIdx.x;
    if (i < e) {
        int d = dst[i];
        int p = atomicAdd(&cursor[d], 1);
        col_src[p] = src[i];
    }
}

// ---- GEMM + fused BN/ELU on input + fused alpha via extra MFMA ----
__global__ __launch_bounds__(256) void k_gemm(const float* __restrict__ Xf,
                                              const float* __restrict__ stats,   // null if !apply_bn
                                              const float* __restrict__ gamma,
                                              const float* __restrict__ beta,
                                              const __hip_bfloat16* __restrict__ Wt,
                                              const __hip_bfloat16* __restrict__ WAT,
                                              __hip_bfloat16* __restrict__ Hb,
                                              float* __restrict__ AS, float* __restrict__ AD,
                                              int n_nodes, int apply_bn) {
    __shared__ float s_scale[128], s_shift[128];
    if (apply_bn && threadIdx.x < 128) {
        int c = threadIdx.x;
        float invN = 1.0f / (float)N_NODES;
        float mu = stats[c] * invN;
        float var = stats[128 + c] * invN - mu * mu;
        float sc = rsqrtf(var + BN_EPS) * gamma[c];
        s_scale[c] = sc;
        s_shift[c] = beta[c] - mu * sc;
    }
    __syncthreads();

    int wave = threadIdx.x >> 6, lane = threadIdx.x & 63;
    int row0 = blockIdx.x * 64 + wave * 16;
    int m_lane = lane & 15, kq = lane >> 4;
    floatx4 acc[8] = {};
    floatx4 acc_a = {};
    const short* Ws = (const short*)Wt;
    const short* Was = (const short*)WAT;
    int r = row0 + m_lane;
    int rr = (r < n_nodes) ? r : 0;
    for (int c = 0; c < 4; c++) {
        const float4* xp = (const float4*)(Xf + (size_t)rr * 128 + c * 32 + kq * 8);
        float4 v0 = xp[0], v1 = xp[1];
        float vals[8] = {v0.x, v0.y, v0.z, v0.w, v1.x, v1.y, v1.z, v1.w};
        short8 a;
        if (apply_bn) {
            int ch0 = c * 32 + kq * 8;
#pragma unroll
            for (int j = 0; j < 8; j++) {
                float val = fmaf(vals[j], s_scale[ch0 + j], s_shift[ch0 + j]);
                val = (val > 0.f) ? val : (__expf(val) - 1.0f);
                a[j] = f2bfs(val);
            }
        } else {
#pragma unroll
            for (int j = 0; j < 8; j++)
                a[j] = f2bfs(vals[j]);
        }
        for (int t = 0; t < 8; t++) {
            short8 b = *(const short8*)(Ws + (t * 16 + m_lane) * 128 + c * 32 + kq * 8);
            acc[t] = __builtin_amdgcn_mfma_f32_16x16x32_bf16(a, b, acc[t], 0, 0, 0);
        }
        short8 bwa = *(const short8*)(Was + m_lane * 128 + c * 32 + kq * 8);
        acc_a = __builtin_amdgcn_mfma_f32_16x16x32_bf16(a, bwa, acc_a, 0, 0, 0);
    }
#pragma unroll
    for (int reg = 0; reg < 4; reg++) {
        int row = row0 + kq * 4 + reg;
        if (row >= n_nodes) continue;
#pragma unroll
        for (int t = 0; t < 8; t++)
            Hb[(size_t)row * 128 + t * 16 + m_lane] = __float2bfloat16(acc[t][reg]);
        float av = acc_a[reg];
        if (m_lane < 8) AS[row * 8 + m_lane] = av;
        else            AD[row * 8 + (m_lane - 8)] = av;
    }
}

// ---- segment softmax + aggregation + FUSED BN partial stats + ticket reduce ----
// Self-cleaning: leaves PAR2 and CNT zeroed on exit (replay/graph safe).
// No spin-waits: last-ticket block does the reduction, others exit.
__global__ __launch_bounds__(256) void k_agg(const int* __restrict__ RP,
                                             const int* __restrict__ COL,
                                             const float* __restrict__ AS,
                                             const float* __restrict__ AD,
                                             const __hip_bfloat16* __restrict__ Hb,
                                             const float* __restrict__ bias,
                                             float* __restrict__ out,
                                             float* __restrict__ par2,
                                             float* __restrict__ stats,
                                             unsigned int* __restrict__ cnt, int n_nodes) {
    __shared__ float s_sum[4][128];
    __shared__ float s_sq[4][128];
    __shared__ int s_last;
    int wave = threadIdx.x >> 6, lane = threadIdx.x & 63;
    int n = blockIdx.x * 4 + wave;
    bool valid = (n < n_nodes);
    int e_l = lane >> 4, q = lane & 15, h = q >> 1;
    // zero this wave's LDS slots (wave-coherent, no barrier needed yet)
    s_sum[wave][lane] = 0.f; s_sum[wave][lane + 64] = 0.f;
    s_sq[wave][lane] = 0.f;  s_sq[wave][lane + 64] = 0.f;

    int p0 = valid ? RP[n] : 0;
    int p1 = valid ? RP[n + 1] : 0;
    float ad = valid ? AD[n * 8 + h] : 0.f;
    float z = 0.f;
    float acc[8];
#pragma unroll
    for (int c = 0; c < 8; c++) acc[c] = 0.f;
    const unsigned short* Hu = (const unsigned short*)Hb;
    for (int p = p0 + e_l; p < p1; p += 4) {
        int s = COL[p];
        float e = AS[s * 8 + h] + ad;
        e = (e > 0.f) ? e : NEG_SLOPE * e;
        float w = __expf(e);   // no max-subtract: |e| << 80, safe in fp32
        z += w;
        const uint4 hv = *(const uint4*)(Hu + (size_t)s * 128 + q * 8);
        acc[0] += w * bf_lo(hv.x); acc[1] += w * bf_hi(hv.x);
        acc[2] += w * bf_lo(hv.y); acc[3] += w * bf_hi(hv.y);
        acc[4] += w * bf_lo(hv.z); acc[5] += w * bf_hi(hv.z);
        acc[6] += w * bf_lo(hv.w); acc[7] += w * bf_hi(hv.w);
    }
    // butterfly over the 4 edge-groups (lane bits 4..5)
#pragma unroll
    for (int off = 16; off < 64; off <<= 1) {
        z += __shfl_xor(z, off, 64);
#pragma unroll
        for (int c = 0; c < 8; c++) acc[c] += __shfl_xor(acc[c], off, 64);
    }
    if (valid && e_l == 0) {
        float inv = 1.0f / (z + 1e-16f);
        const float* bp = bias + q * 8;
        float v[8];
#pragma unroll
        for (int c = 0; c < 8; c++) v[c] = fmaf(acc[c], inv, bp[c]);
        float4* op = (float4*)(out + (size_t)n * 128 + q * 8);
        op[0] = make_float4(v[0], v[1], v[2], v[3]);
        op[1] = make_float4(v[4], v[5], v[6], v[7]);
        int ch0 = q * 8;
#pragma unroll
        for (int c = 0; c < 8; c++) {
            s_sum[wave][ch0 + c] = v[c];
            s_sq[wave][ch0 + c] = v[c] * v[c];
        }
    }
    __syncthreads();
    int tid = threadIdx.x;
    float tot;
    if (tid < 128) {
        tot = s_sum[0][tid] + s_sum[1][tid] + s_sum[2][tid] + s_sum[3][tid];
    } else {
        int cc = tid - 128;
        tot = s_sq[0][cc] + s_sq[1][cc] + s_sq[2][cc] + s_sq[3][cc];
    }
    atomicAdd(&par2[(blockIdx.x & 63) * 256 + tid], tot);
    __threadfence();           // my atomic reached the coherent point
    __syncthreads();           // whole block's atomics fenced
    if (tid == 0) {
        unsigned int old = atomicAdd(cnt, 1u);
        s_last = (old == gridDim.x - 1) ? 1 : 0;
    }
    __syncthreads();
    if (s_last) {
        // last block: reduce 64 banked rows -> stats, re-zeroing PAR2 in the
        // same atomicExch (atomic-to-atomic is device-coherent across XCDs).
        float s = 0.f;
#pragma unroll 8
        for (int b = 0; b < 64; b++)
            s += atomicExch(&par2[b * 256 + tid], 0.f);
        stats[tid] = s;        // visible to next kernel via dispatch boundary
        if (tid == 0) atomicExch(cnt, 0u);
    }
}

// ---------------- final BN apply + ELU -> fp32 out ----------------
__global__ void k_bnapply(const float* __restrict__ x, const float* __restrict__ stats,
                          const float* __restrict__ gamma, const float* __restrict__ beta,
                          float* __restrict__ outf, int n_nodes) {
    int i = blockIdx.x * 256 + threadIdx.x;   // each handles 4 channels
    if (i >= n_nodes * 32) return;
    float4 v = *(const float4*)(x + (size_t)i * 4);
    int c0 = (i * 4) & 127;
    float r[4] = {v.x, v.y, v.z, v.w};
    float invN = 1.0f / (float)N_NODES;
#pragma unroll
    for (int j = 0; j < 4; j++) {
        int c = c0 + j;
        float mu = stats[c] * invN;
        float var = stats[128 + c] * invN - mu * mu;
        float sc = rsqrtf(var + BN_EPS) * gamma[c];
        float val = (r[j] - mu) * sc + beta[c];
        val = (val > 0.f) ? val : (__expf(val) - 1.0f);
        r[j] = val;
    }
    *(float4*)(outf + (size_t)i * 4) = make_float4(r[0], r[1], r[2], r[3]);
}

extern "C" void kernel_launch(void* const* d_in, const int* in_sizes, int n_in,
                              void* d_out, int out_size, void* d_ws, size_t ws_size,
                              hipStream_t stream) {
    const float* x_in   = (const float*)d_in[0];
    const int*   eidx   = (const int*)d_in[1];
    const float* W      = (const float*)d_in[2];
    const float* attsrc = (const float*)d_in[3];
    const float* attdst = (const float*)d_in[4];
    const float* bias   = (const float*)d_in[5];
    const float* gamma  = (const float*)d_in[6];
    const float* beta   = (const float*)d_in[7];
    float* out = (float*)d_out;

    const int N = N_NODES, E = N_EDGES;
    const int* src = eidx;
    const int* dst = eidx + E;

    // workspace carve-up
    char* base = (char*)d_ws;
    size_t off = 0;
    auto carve = [&](size_t bytes) -> char* {
        char* p = base + off;
        off += (bytes + 255) & ~(size_t)255;
        return p;
    };
    __hip_bfloat16* Hb  = (__hip_bfloat16*)carve((size_t)N * HID * 2);
    float*          XN  = (float*)carve((size_t)N * HID * 4);
    float*          AS  = (float*)carve((size_t)N * HEADS * 4);
    float*          AD  = (float*)carve((size_t)N * HEADS * 4);
    __hip_bfloat16* WT  = (__hip_bfloat16*)carve((size_t)3 * HID * HID * 2);
    __hip_bfloat16* WAT = (__hip_bfloat16*)carve((size_t)3 * 16 * HID * 2);
    float*          STA = (float*)carve(3 * 256 * 4);
    // DEG, PAR2, CNT are contiguous so ONE memset zeroes all three
    int*            DEG = (int*)carve((size_t)N * 4);
    float*          PAR2 = (float*)carve(64 * 256 * 4);       // banked BN partials
    unsigned int*   CNT = (unsigned int*)carve(256);          // ticket counter
    int*            INC = (int*)carve((size_t)N * 4);
    int*            RP  = (int*)carve((size_t)(N + 1) * 4);
    int*            CUR = (int*)carve((size_t)N * 4);
    int*            PRT = (int*)carve(1024 * 4);
    int*            COL = (int*)carve((size_t)E * 4);

    const int NB_E  = (E + 255) / 256;
    const int NB_SC = (N + 511) / 512;   // 98
    const int PREP_B = (3 * 16384 + 3 * 2048 + 255) / 256;   // 216

    // ---- zero DEG + PAR2 + CNT in one memset (contiguous carves) ----
    size_t zlen = (size_t)((char*)(CNT) + 256 - (char*)DEG);
    (void)hipMemsetAsync(DEG, 0, zlen, stream);

    // ---- CSR build (once) fused with weight prep ----
    k_hist_prep<<<NB_E + PREP_B, 256, 0, stream>>>(dst, DEG, E, NB_E, W, attsrc, attdst, WT, WAT);
    k_scan1<<<NB_SC, 512, 0, stream>>>(DEG, INC, PRT, N);
    k_scan23<<<NB_SC, 512, 0, stream>>>(DEG, INC, PRT, RP, CUR, N, E, NB_SC);
    k_scatter<<<NB_E, 256, 0, stream>>>(src, dst, CUR, COL, E);

    for (int l = 0; l < 3; l++) {
        const float* Xf = (l == 0) ? x_in : XN;
        const float* st = (l == 0) ? nullptr : (STA + (l - 1) * 256);
        const float* gm = gamma + (l - 1) * 128;   // unused when l==0
        const float* bt = beta + (l - 1) * 128;
        k_gemm<<<(N + 63) / 64, 256, 0, stream>>>(Xf, st, gm, bt,
                                                  WT + l * 16384, WAT + l * 2048,
                                                  Hb, AS, AD, N, (l == 0) ? 0 : 1);
        k_agg<<<(N + 3) / 4, 256, 0, stream>>>(RP, COL, AS, AD, Hb, bias + l * 128,
                                               XN, PAR2, STA + l * 256, CNT, N);
    }
    k_bnapply<<<(N * 32 + 255) / 256, 256, 0, stream>>>(XN, STA + 2 * 256,
                                                        gamma + 2 * 128, beta + 2 * 128, out, N);
}

// Round 5
// 362.045 us; speedup vs baseline: 10.4100x; 10.4100x over previous
//
#include <hip/hip_runtime.h>
#include <hip/hip_bf16.h>

#define N_NODES 50000
#define N_EDGES 600000
#define HID 128
#define HEADS 8
#define OUTC 16
#define NEG_SLOPE 0.2f
#define BN_EPS 1e-5f

typedef __attribute__((ext_vector_type(8))) short short8;
typedef __attribute__((ext_vector_type(4))) float floatx4;

__device__ __forceinline__ float bf_lo(unsigned int v) { return __uint_as_float(v << 16); }
__device__ __forceinline__ float bf_hi(unsigned int v) { return __uint_as_float(v & 0xffff0000u); }

__device__ __forceinline__ short f2bfs(float v) {
    __hip_bfloat16 b = __float2bfloat16(v);
    return *reinterpret_cast<short*>(&b);
}

// ---------------- fused: edge histogram + weight prep ----------------
__global__ void k_hist_prep(const int* __restrict__ dst, int* __restrict__ deg, int e, int nb_e,
                            const float* __restrict__ W, const float* __restrict__ asrc,
                            const float* __restrict__ adst,
                            __hip_bfloat16* __restrict__ Wt, __hip_bfloat16* __restrict__ WAT) {
    if ((int)blockIdx.x < nb_e) {
        int i = blockIdx.x * 256 + threadIdx.x;
        if (i < e) atomicAdd(&deg[dst[i]], 1);
        return;
    }
    int i = (blockIdx.x - nb_e) * 256 + threadIdx.x;
    if (i < 3 * 16384) {
        int l = i >> 14, r = i & 16383, n = r >> 7, k = r & 127;
        Wt[i] = __float2bfloat16(W[l * 16384 + k * 128 + n]);
    } else {
        int j2 = i - 3 * 16384;
        if (j2 < 3 * 2048) {
            int l = j2 >> 11, r = j2 & 2047, j = r >> 7, k = r & 127;
            const float* att = (j < 8) ? (asrc + l * 128 + j * 16) : (adst + l * 128 + (j - 8) * 16);
            const float* Wrow = W + l * 16384 + k * 128 + (j & 7) * 16;
            float sum = 0.f;
#pragma unroll
            for (int c = 0; c < 16; c++) sum += Wrow[c] * att[c];
            WAT[j2] = __float2bfloat16(sum);
        }
    }
}

// ---------------- CSR scans ----------------
__global__ void k_scan1(const int* __restrict__ deg, int* __restrict__ incl,
                        int* __restrict__ partials, int n) {
    __shared__ int sh[512];
    int i = blockIdx.x * 512 + threadIdx.x;
    int v = (i < n) ? deg[i] : 0;
    sh[threadIdx.x] = v;
    __syncthreads();
    for (int off = 1; off < 512; off <<= 1) {
        int t = (threadIdx.x >= off) ? sh[threadIdx.x - off] : 0;
        __syncthreads();
        sh[threadIdx.x] += t;
        __syncthreads();
    }
    if (i < n) incl[i] = sh[threadIdx.x];
    if (threadIdx.x == 511) partials[blockIdx.x] = sh[511];
}

// fused scan2+scan3: every block redundantly exclusive-scans the (<=128)
// block partials in LDS, then applies its own offset.
__global__ void k_scan23(const int* __restrict__ deg, const int* __restrict__ incl,
                         const int* __restrict__ partials, int* __restrict__ row_ptr,
                         int* __restrict__ cursor, int n, int e_total, int nb) {
    __shared__ int sp[128];
    int t = threadIdx.x;   // 512
    int orig = 0;
    if (t < 128) {
        orig = (t < nb) ? partials[t] : 0;
        sp[t] = orig;
    }
    __syncthreads();
    for (int off = 1; off < 128; off <<= 1) {
        int v = (t < 128 && t >= off) ? sp[t - off] : 0;
        __syncthreads();
        if (t < 128) sp[t] += v;
        __syncthreads();
    }
    if (t < 128) sp[t] -= orig;   // exclusive
    __syncthreads();
    int i = blockIdx.x * 512 + t;
    if (i < n) {
        int rp = incl[i] - deg[i] + sp[blockIdx.x];
        row_ptr[i] = rp;
        cursor[i] = rp;
    }
    if (i == 0) row_ptr[n] = e_total;
}

__global__ void k_scatter(const int* __restrict__ src, const int* __restrict__ dst,
                          int* __restrict__ cursor, int* __restrict__ col_src, int e) {
    int i = blockIdx.x * 256 + threadIdx.x;
    if (i < e) {
        int d = dst[i];
        int p = atomicAdd(&cursor[d], 1);
        col_src[p] = src[i];
    }
}

// ---- GEMM + fused BN/ELU on input + fused alpha via extra MFMA ----
__global__ __launch_bounds__(256) void k_gemm(const float* __restrict__ Xf,
                                              const float* __restrict__ stats,   // null if !apply_bn
                                              const float* __restrict__ gamma,
                                              const float* __restrict__ beta,
                                              const __hip_bfloat16* __restrict__ Wt,
                                              const __hip_bfloat16* __restrict__ WAT,
                                              __hip_bfloat16* __restrict__ Hb,
                                              float* __restrict__ AS, float* __restrict__ AD,
                                              int n_nodes, int apply_bn) {
    __shared__ float s_scale[128], s_shift[128];
    if (apply_bn && threadIdx.x < 128) {
        int c = threadIdx.x;
        float invN = 1.0f / (float)N_NODES;
        float mu = stats[c] * invN;
        float var = stats[128 + c] * invN - mu * mu;
        float sc = rsqrtf(var + BN_EPS) * gamma[c];
        s_scale[c] = sc;
        s_shift[c] = beta[c] - mu * sc;
    }
    __syncthreads();

    int wave = threadIdx.x >> 6, lane = threadIdx.x & 63;
    int row0 = blockIdx.x * 64 + wave * 16;
    int m_lane = lane & 15, kq = lane >> 4;
    floatx4 acc[8] = {};
    floatx4 acc_a = {};
    const short* Ws = (const short*)Wt;
    const short* Was = (const short*)WAT;
    int r = row0 + m_lane;
    int rr = (r < n_nodes) ? r : 0;
    for (int c = 0; c < 4; c++) {
        const float4* xp = (const float4*)(Xf + (size_t)rr * 128 + c * 32 + kq * 8);
        float4 v0 = xp[0], v1 = xp[1];
        float vals[8] = {v0.x, v0.y, v0.z, v0.w, v1.x, v1.y, v1.z, v1.w};
        short8 a;
        if (apply_bn) {
            int ch0 = c * 32 + kq * 8;
#pragma unroll
            for (int j = 0; j < 8; j++) {
                float val = fmaf(vals[j], s_scale[ch0 + j], s_shift[ch0 + j]);
                val = (val > 0.f) ? val : (__expf(val) - 1.0f);
                a[j] = f2bfs(val);
            }
        } else {
#pragma unroll
            for (int j = 0; j < 8; j++)
                a[j] = f2bfs(vals[j]);
        }
        for (int t = 0; t < 8; t++) {
            short8 b = *(const short8*)(Ws + (t * 16 + m_lane) * 128 + c * 32 + kq * 8);
            acc[t] = __builtin_amdgcn_mfma_f32_16x16x32_bf16(a, b, acc[t], 0, 0, 0);
        }
        short8 bwa = *(const short8*)(Was + m_lane * 128 + c * 32 + kq * 8);
        acc_a = __builtin_amdgcn_mfma_f32_16x16x32_bf16(a, bwa, acc_a, 0, 0, 0);
    }
#pragma unroll
    for (int reg = 0; reg < 4; reg++) {
        int row = row0 + kq * 4 + reg;
        if (row >= n_nodes) continue;
#pragma unroll
        for (int t = 0; t < 8; t++)
            Hb[(size_t)row * 128 + t * 16 + m_lane] = __float2bfloat16(acc[t][reg]);
        float av = acc_a[reg];
        if (m_lane < 8) AS[row * 8 + m_lane] = av;
        else            AD[row * 8 + (m_lane - 8)] = av;
    }
}

// ---- segment softmax + aggregation + FUSED BN partial stats ----
// mapping: e_l = lane>>4 (4 edge groups), q = lane&15, head h = q>>1,
// each lane owns 8 channels (ch0 = q*8).
// Tail: blocks atomicAdd 256 partials into PAR2[bid&63][256].
// NO __threadfence() here: a device-scope fence on gfx950 writes back /
// invalidates the per-XCD L2 and destroyed gather locality (measured:
// k_agg 42us -> 1200us, FETCH 78MB, VALUBusy 1.3%). The separate 1-block
// k_bnreduce kernel is far cheaper than any in-kernel fenced reduction.
__global__ __launch_bounds__(256) void k_agg(const int* __restrict__ RP,
                                             const int* __restrict__ COL,
                                             const float* __restrict__ AS,
                                             const float* __restrict__ AD,
                                             const __hip_bfloat16* __restrict__ Hb,
                                             const float* __restrict__ bias,
                                             float* __restrict__ out,
                                             float* __restrict__ par2, int n_nodes) {
    __shared__ float s_sum[4][128];
    __shared__ float s_sq[4][128];
    int wave = threadIdx.x >> 6, lane = threadIdx.x & 63;
    int n = blockIdx.x * 4 + wave;
    bool valid = (n < n_nodes);
    int e_l = lane >> 4, q = lane & 15, h = q >> 1;
    // zero this wave's LDS slots (wave-coherent, no barrier needed yet)
    s_sum[wave][lane] = 0.f; s_sum[wave][lane + 64] = 0.f;
    s_sq[wave][lane] = 0.f;  s_sq[wave][lane + 64] = 0.f;

    int p0 = valid ? RP[n] : 0;
    int p1 = valid ? RP[n + 1] : 0;
    float ad = valid ? AD[n * 8 + h] : 0.f;
    float z = 0.f;
    float acc[8];
#pragma unroll
    for (int c = 0; c < 8; c++) acc[c] = 0.f;
    const unsigned short* Hu = (const unsigned short*)Hb;
    for (int p = p0 + e_l; p < p1; p += 4) {
        int s = COL[p];
        float e = AS[s * 8 + h] + ad;
        e = (e > 0.f) ? e : NEG_SLOPE * e;
        float w = __expf(e);   // no max-subtract: |e| << 80, safe in fp32
        z += w;
        const uint4 hv = *(const uint4*)(Hu + (size_t)s * 128 + q * 8);
        acc[0] += w * bf_lo(hv.x); acc[1] += w * bf_hi(hv.x);
        acc[2] += w * bf_lo(hv.y); acc[3] += w * bf_hi(hv.y);
        acc[4] += w * bf_lo(hv.z); acc[5] += w * bf_hi(hv.z);
        acc[6] += w * bf_lo(hv.w); acc[7] += w * bf_hi(hv.w);
    }
    // butterfly over the 4 edge-groups (lane bits 4..5)
#pragma unroll
    for (int off = 16; off < 64; off <<= 1) {
        z += __shfl_xor(z, off, 64);
#pragma unroll
        for (int c = 0; c < 8; c++) acc[c] += __shfl_xor(acc[c], off, 64);
    }
    if (valid && e_l == 0) {
        float inv = 1.0f / (z + 1e-16f);
        const float* bp = bias + q * 8;
        float v[8];
#pragma unroll
        for (int c = 0; c < 8; c++) v[c] = fmaf(acc[c], inv, bp[c]);
        float4* op = (float4*)(out + (size_t)n * 128 + q * 8);
        op[0] = make_float4(v[0], v[1], v[2], v[3]);
        op[1] = make_float4(v[4], v[5], v[6], v[7]);
        int ch0 = q * 8;
#pragma unroll
        for (int c = 0; c < 8; c++) {
            s_sum[wave][ch0 + c] = v[c];
            s_sq[wave][ch0 + c] = v[c] * v[c];
        }
    }
    __syncthreads();
    int tid = threadIdx.x;
    float tot;
    if (tid < 128) {
        tot = s_sum[0][tid] + s_sum[1][tid] + s_sum[2][tid] + s_sum[3][tid];
    } else {
        int cc = tid - 128;
        tot = s_sq[0][cc] + s_sq[1][cc] + s_sq[2][cc] + s_sq[3][cc];
    }
    atomicAdd(&par2[(blockIdx.x & 63) * 256 + tid], tot);
}

// ---- BN stats reduce: 64 partial rows -> stats[256]; re-zero PAR2 for next use ----
__global__ void k_bnreduce(float* __restrict__ par2, float* __restrict__ stats) {
    int t = threadIdx.x;   // 256
    float s = 0.f;
#pragma unroll 8
    for (int b = 0; b < 64; b++) s += par2[b * 256 + t];
    stats[t] = s;
#pragma unroll 8
    for (int b = 0; b < 64; b++) par2[b * 256 + t] = 0.f;
}

// ---------------- final BN apply + ELU -> fp32 out ----------------
__global__ void k_bnapply(const float* __restrict__ x, const float* __restrict__ stats,
                          const float* __restrict__ gamma, const float* __restrict__ beta,
                          float* __restrict__ outf, int n_nodes) {
    int i = blockIdx.x * 256 + threadIdx.x;   // each handles 4 channels
    if (i >= n_nodes * 32) return;
    float4 v = *(const float4*)(x + (size_t)i * 4);
    int c0 = (i * 4) & 127;
    float r[4] = {v.x, v.y, v.z, v.w};
    float invN = 1.0f / (float)N_NODES;
#pragma unroll
    for (int j = 0; j < 4; j++) {
        int c = c0 + j;
        float mu = stats[c] * invN;
        float var = stats[128 + c] * invN - mu * mu;
        float sc = rsqrtf(var + BN_EPS) * gamma[c];
        float val = (r[j] - mu) * sc + beta[c];
        val = (val > 0.f) ? val : (__expf(val) - 1.0f);
        r[j] = val;
    }
    *(float4*)(outf + (size_t)i * 4) = make_float4(r[0], r[1], r[2], r[3]);
}

extern "C" void kernel_launch(void* const* d_in, const int* in_sizes, int n_in,
                              void* d_out, int out_size, void* d_ws, size_t ws_size,
                              hipStream_t stream) {
    const float* x_in   = (const float*)d_in[0];
    const int*   eidx   = (const int*)d_in[1];
    const float* W      = (const float*)d_in[2];
    const float* attsrc = (const float*)d_in[3];
    const float* attdst = (const float*)d_in[4];
    const float* bias   = (const float*)d_in[5];
    const float* gamma  = (const float*)d_in[6];
    const float* beta   = (const float*)d_in[7];
    float* out = (float*)d_out;

    const int N = N_NODES, E = N_EDGES;
    const int* src = eidx;
    const int* dst = eidx + E;

    // workspace carve-up
    char* base = (char*)d_ws;
    size_t off = 0;
    auto carve = [&](size_t bytes) -> char* {
        char* p = base + off;
        off += (bytes + 255) & ~(size_t)255;
        return p;
    };
    __hip_bfloat16* Hb  = (__hip_bfloat16*)carve((size_t)N * HID * 2);
    float*          XN  = (float*)carve((size_t)N * HID * 4);
    float*          AS  = (float*)carve((size_t)N * HEADS * 4);
    float*          AD  = (float*)carve((size_t)N * HEADS * 4);
    __hip_bfloat16* WT  = (__hip_bfloat16*)carve((size_t)3 * HID * HID * 2);
    __hip_bfloat16* WAT = (__hip_bfloat16*)carve((size_t)3 * 16 * HID * 2);
    float*          STA = (float*)carve(3 * 256 * 4);
    // DEG and PAR2 are contiguous so ONE memset zeroes both
    int*            DEG = (int*)carve((size_t)N * 4);
    float*          PAR2 = (float*)carve(64 * 256 * 4);       // banked BN partials
    int*            INC = (int*)carve((size_t)N * 4);
    int*            RP  = (int*)carve((size_t)(N + 1) * 4);
    int*            CUR = (int*)carve((size_t)N * 4);
    int*            PRT = (int*)carve(1024 * 4);
    int*            COL = (int*)carve((size_t)E * 4);

    const int NB_E  = (E + 255) / 256;
    const int NB_SC = (N + 511) / 512;   // 98
    const int PREP_B = (3 * 16384 + 3 * 2048 + 255) / 256;   // 216

    // ---- zero DEG + PAR2 in one memset (contiguous carves) ----
    size_t zlen = (size_t)((char*)(PAR2 + 64 * 256) - (char*)DEG);
    (void)hipMemsetAsync(DEG, 0, zlen, stream);

    // ---- CSR build (once) fused with weight prep ----
    k_hist_prep<<<NB_E + PREP_B, 256, 0, stream>>>(dst, DEG, E, NB_E, W, attsrc, attdst, WT, WAT);
    k_scan1<<<NB_SC, 512, 0, stream>>>(DEG, INC, PRT, N);
    k_scan23<<<NB_SC, 512, 0, stream>>>(DEG, INC, PRT, RP, CUR, N, E, NB_SC);
    k_scatter<<<NB_E, 256, 0, stream>>>(src, dst, CUR, COL, E);

    for (int l = 0; l < 3; l++) {
        const float* Xf = (l == 0) ? x_in : XN;
        const float* st = (l == 0) ? nullptr : (STA + (l - 1) * 256);
        const float* gm = gamma + (l - 1) * 128;   // unused when l==0
        const float* bt = beta + (l - 1) * 128;
        k_gemm<<<(N + 63) / 64, 256, 0, stream>>>(Xf, st, gm, bt,
                                                  WT + l * 16384, WAT + l * 2048,
                                                  Hb, AS, AD, N, (l == 0) ? 0 : 1);
        k_agg<<<(N + 3) / 4, 256, 0, stream>>>(RP, COL, AS, AD, Hb, bias + l * 128,
                                               XN, PAR2, N);
        k_bnreduce<<<1, 256, 0, stream>>>(PAR2, STA + l * 256);
    }
    k_bnapply<<<(N * 32 + 255) / 256, 256, 0, stream>>>(XN, STA + 2 * 256,
                                                        gamma + 2 * 128, beta + 2 * 128, out, N);
}